// Round 12
// baseline (95.212 us; speedup 1.0000x reference)
//
#include <hip/hip_runtime.h>
#include <math.h>

#define NL    4096      // coarse points
#define NH    16384     // fine points
#define NF4   64        // 256 features / 4
#define BLK   1024      // threads (16 waves)
#define NW    16
#define FPB   64        // fine points per block (lane = fine point)
#define PERW  (NL / NW) // 256 candidates per wave
#define TOPM  5         // quantized-key shortlist size
#define SENT  0x7fffffff

typedef float v2f __attribute__((ext_vector_type(2)));

// ---- i32 sorted top-5. Keys = (d2-bits & 0xFFFFF000) | j. i32 order puts
// negative-d2 rounding noise first (harmless; exact rescore follows).
__device__ __forceinline__ int med3i(int a, int b, int c)
{
  int d;
  asm("v_med3_i32 %0, %1, %2, %3" : "=v"(d) : "v"(a), "v"(b), "v"(c));
  return d;
}
__device__ __forceinline__ int mini(int a, int b)
{
  int d;
  asm("v_min_i32 %0, %1, %2" : "=v"(d) : "v"(a), "v"(b));
  return d;
}
__device__ __forceinline__ void ins5(int k, int& b0, int& b1, int& b2,
                                     int& b3, int& b4)
{
  const int n0 = mini(b0, k);
  const int n1 = med3i(k, b0, b1);
  const int n2 = med3i(k, b1, b2);
  const int n3 = med3i(k, b2, b3);
  const int n4 = med3i(k, b3, b4);
  b0 = n0; b1 = n1; b2 = n2; b3 = n3; b4 = n4;
}

// Lexicographic (d, j) insert for the exact fp32 rescore (top-3).
__device__ __forceinline__ void lexins3(float d, int j,
    float& b0, float& b1, float& b2, int& i0, int& i1, int& i2)
{
  bool s2 = (d < b2) || ((d == b2) && (j < i2));
  b2 = s2 ? d : b2;  i2 = s2 ? j : i2;
  bool s1 = (b2 < b1) || ((b2 == b1) && (i2 < i1));
  float tf = b1; int ti = i1;
  b1 = s1 ? b2 : b1;  i1 = s1 ? i2 : i1;
  b2 = s1 ? tf : b2;  i2 = s1 ? ti : i2;
  bool s0 = (b1 < b0) || ((b1 == b0) && (i1 < i0));
  tf = b0; ti = i0;
  b0 = s0 ? b1 : b0;  i0 = s0 ? i1 : i0;
  b1 = s0 ? tf : b1;  i1 = s0 ? ti : i1;
}

// Packed distance, per-component bit-identical to the reference sequence:
//   dot = fma(h2,lz, fma(h1,ly, mul(h0,lx)));  d2 = add(fma(dot,-2,hh), ll)
__device__ __forceinline__ v2f dist2_pk(v2f lx, v2f ly, v2f lz, v2f ll,
                                        v2f h00, v2f h11, v2f h22, v2f hhh,
                                        v2f m22)
{
  v2f d;
  asm("v_pk_mul_f32 %0, %1, %2\n\t"
      "v_pk_fma_f32 %0, %3, %4, %0\n\t"
      "v_pk_fma_f32 %0, %5, %6, %0\n\t"
      "v_pk_fma_f32 %0, %0, %7, %8\n\t"
      "v_pk_add_f32 %0, %0, %9"
      : "=&v"(d)
      : "v"(h00), "s"(lx), "v"(h11), "s"(ly), "v"(h22), "s"(lz),
        "v"(m22), "v"(hhh), "s"(ll));
  return d;
}

// 8-candidate chunk: 16 s_load_dwordx2 — each PAIR lands directly in its own
// aligned SGPR pair (v2f), so dist2_pk's "s" operands need ZERO extraction
// s_movs (the round-9..11 issue-slot bloat).
#define LOAD16(X0,X1,X2,X3,Y0,Y1,Y2,Y3,Z0,Z1,Z2,Z3,W0,W1,W2,W3,P)  \
  asm volatile("s_load_dwordx2 %0, %16, 0x0\n\t"                    \
               "s_load_dwordx2 %1, %16, 0x8\n\t"                    \
               "s_load_dwordx2 %2, %16, 0x10\n\t"                   \
               "s_load_dwordx2 %3, %16, 0x18\n\t"                   \
               "s_load_dwordx2 %4, %16, 0x4000\n\t"                 \
               "s_load_dwordx2 %5, %16, 0x4008\n\t"                 \
               "s_load_dwordx2 %6, %16, 0x4010\n\t"                 \
               "s_load_dwordx2 %7, %16, 0x4018\n\t"                 \
               "s_load_dwordx2 %8, %16, 0x8000\n\t"                 \
               "s_load_dwordx2 %9, %16, 0x8008\n\t"                 \
               "s_load_dwordx2 %10, %16, 0x8010\n\t"                \
               "s_load_dwordx2 %11, %16, 0x8018\n\t"                \
               "s_load_dwordx2 %12, %16, 0xc000\n\t"                \
               "s_load_dwordx2 %13, %16, 0xc008\n\t"                \
               "s_load_dwordx2 %14, %16, 0xc010\n\t"                \
               "s_load_dwordx2 %15, %16, 0xc018"                    \
               : "=&s"(X0), "=&s"(X1), "=&s"(X2), "=&s"(X3),        \
                 "=&s"(Y0), "=&s"(Y1), "=&s"(Y2), "=&s"(Y3),        \
                 "=&s"(Z0), "=&s"(Z1), "=&s"(Z2), "=&s"(Z3),        \
                 "=&s"(W0), "=&s"(W1), "=&s"(W2), "=&s"(W3)         \
               : "s"(P))
// Wait-all, dataflow-tied (SMEM returns OOO; ties pin liveness — R10 lesson).
#define WAIT16(X0,X1,X2,X3,Y0,Y1,Y2,Y3,Z0,Z1,Z2,Z3,W0,W1,W2,W3)    \
  asm volatile("s_waitcnt lgkmcnt(0)"                               \
               : "+s"(X0), "+s"(X1), "+s"(X2), "+s"(X3),            \
                 "+s"(Y0), "+s"(Y1), "+s"(Y2), "+s"(Y3),            \
                 "+s"(Z0), "+s"(Z1), "+s"(Z2), "+s"(Z3),            \
                 "+s"(W0), "+s"(W1), "+s"(W2), "+s"(W3))

// ---------- prologue: SoA pack (x | y | z | ll), exact np rounding ----------
__global__ __launch_bounds__(256)
void prep_soa_kernel(const float* __restrict__ pos_l, float* __restrict__ cand)
{
  const int i = blockIdx.x * 256 + threadIdx.x;   // 0..NL-1
  const float l0 = pos_l[i * 3 + 0];
  const float l1 = pos_l[i * 3 + 1];
  const float l2 = pos_l[i * 3 + 2];
  const float ll = __fadd_rn(__fadd_rn(__fmul_rn(l0, l0), __fmul_rn(l1, l1)),
                             __fmul_rn(l2, l2));
  cand[i]          = l0;
  cand[NL + i]     = l1;
  cand[2 * NL + i] = l2;
  cand[3 * NL + i] = ll;
}

// ---------- main: quantized-key scan + exact rescore + interpolate ----------
__global__ __launch_bounds__(BLK)
void knn_interp_kernel(const float* __restrict__ x,
                       const float* __restrict__ pos_l,
                       const float* __restrict__ pos_h,
                       const float* __restrict__ cand,   // SoA x|y|z|ll
                       float* __restrict__ out)
{
  __shared__ int   pk_[NW * FPB * TOPM];   // 20 KB partial shortlists
  __shared__ float wn[FPB * 3];
  __shared__ int   sj[FPB * 3];

  const int tid  = threadIdx.x;
  const int lane = tid & 63;
  const int wv   = __builtin_amdgcn_readfirstlane(tid >> 6);
  const int fg   = blockIdx.x * FPB + lane;

  const float h0 = pos_h[fg * 3 + 0];
  const float h1 = pos_h[fg * 3 + 1];
  const float h2 = pos_h[fg * 3 + 2];
  const float hh = __fadd_rn(__fadd_rn(__fmul_rn(h0, h0), __fmul_rn(h1, h1)),
                             __fmul_rn(h2, h2));
  const v2f h00 = { h0, h0 }, h11 = { h1, h1 }, h22 = { h2, h2 };
  const v2f hhh = { hh, hh }, m22 = { -2.0f, -2.0f };

  unsigned int kmaskv;
  asm("v_mov_b32 %0, 0xfffff000" : "=v"(kmaskv));

  int a0 = SENT, a1 = SENT, a2 = SENT, a3 = SENT, a4 = SENT;
  int c0 = SENT, c1 = SENT, c2 = SENT, c3 = SENT, c4 = SENT;

  const int jbase = __builtin_amdgcn_readfirstlane(wv * PERW);

#define EVPAIR(LX, LY, LZ, LW, J0)                                         \
  do {                                                                     \
    const v2f d = dist2_pk(LX, LY, LZ, LW, h00, h11, h22, hhh, m22);       \
    const int j0_ = (J0);                                                  \
    const int j1_ = j0_ + 1;                                               \
    int k0_, k1_;                                                          \
    asm("v_and_or_b32 %0, %1, %2, %3"                                      \
        : "=v"(k0_) : "v"(d.x), "v"(kmaskv), "s"(j0_));                    \
    asm("v_and_or_b32 %0, %1, %2, %3"                                      \
        : "=v"(k1_) : "v"(d.y), "v"(kmaskv), "s"(j1_));                    \
    ins5(k0_, a0, a1, a2, a3, a4);                                         \
    ins5(k1_, c0, c1, c2, c3, c4);                                         \
  } while (0)

#define EVAL8(X0,X1,X2,X3,Y0,Y1,Y2,Y3,Z0,Z1,Z2,Z3,W0,W1,W2,W3,JB)         \
  do {                                                                     \
    EVPAIR(X0, Y0, Z0, W0, (JB) + 0);                                      \
    EVPAIR(X1, Y1, Z1, W1, (JB) + 2);                                      \
    EVPAIR(X2, Y2, Z2, W2, (JB) + 4);                                      \
    EVPAIR(X3, Y3, Z3, W3, (JB) + 6);                                      \
  } while (0)

  // software-pipelined scan: 8-cand chunks, double-buffered direct-v2f loads
  {
    v2f ax0, ax1, ax2, ax3, ay0, ay1, ay2, ay3;
    v2f az0, az1, az2, az3, aw0, aw1, aw2, aw3;
    v2f bx0, bx1, bx2, bx3, by0, by1, by2, by3;
    v2f bz0, bz1, bz2, bz3, bw0, bw1, bw2, bw3;
    LOAD16(ax0,ax1,ax2,ax3,ay0,ay1,ay2,ay3,az0,az1,az2,az3,
           aw0,aw1,aw2,aw3, cand + jbase);
    for (int t = 0; t < PERW; t += 16) {
      WAIT16(ax0,ax1,ax2,ax3,ay0,ay1,ay2,ay3,az0,az1,az2,az3,
             aw0,aw1,aw2,aw3);
      LOAD16(bx0,bx1,bx2,bx3,by0,by1,by2,by3,bz0,bz1,bz2,bz3,
             bw0,bw1,bw2,bw3, cand + jbase + t + 8);
      EVAL8(ax0,ax1,ax2,ax3,ay0,ay1,ay2,ay3,az0,az1,az2,az3,
            aw0,aw1,aw2,aw3, jbase + t);
      WAIT16(bx0,bx1,bx2,bx3,by0,by1,by2,by3,bz0,bz1,bz2,bz3,
             bw0,bw1,bw2,bw3);
      LOAD16(ax0,ax1,ax2,ax3,ay0,ay1,ay2,ay3,az0,az1,az2,az3,
             aw0,aw1,aw2,aw3, cand + jbase + t + 16);  // final iter: dead pref
      EVAL8(bx0,bx1,bx2,bx3,by0,by1,by2,by3,bz0,bz1,bz2,bz3,
            bw0,bw1,bw2,bw3, jbase + t + 8);
    }
    // drain the dead prefetch — in-flight returns must not clobber
    // reallocated SGPRs (round-10 failure mode)
    WAIT16(ax0,ax1,ax2,ax3,ay0,ay1,ay2,ay3,az0,az1,az2,az3,
           aw0,aw1,aw2,aw3);
  }
#undef EVAL8
#undef EVPAIR

  // merge odd-set into even-set (value-based, order-independent)
  ins5(c0, a0, a1, a2, a3, a4);
  ins5(c1, a0, a1, a2, a3, a4);
  ins5(c2, a0, a1, a2, a3, a4);
  ins5(c3, a0, a1, a2, a3, a4);
  ins5(c4, a0, a1, a2, a3, a4);

  {
    const int s = (wv * FPB + lane) * TOPM;
    pk_[s + 0] = a0; pk_[s + 1] = a1; pk_[s + 2] = a2;
    pk_[s + 3] = a3; pk_[s + 4] = a4;
  }
  __syncthreads();

  // first 64 threads: merge NW shortlists, exact rescore, weights
  if (tid < FPB) {
    int m0 = SENT, m1 = SENT, m2 = SENT, m3 = SENT, m4 = SENT;
    for (int w = 0; w < NW; ++w) {
      const int s = (w * FPB + tid) * TOPM;
      #pragma unroll
      for (int q = 0; q < TOPM; ++q)
        ins5(pk_[s + q], m0, m1, m2, m3, m4);
    }

    // exact fp32 expansion-form rescore of the 5 survivors; lex top-3 —
    // replicates the reference's stable top_k exactly.
    float e0 = INFINITY, e1 = INFINITY, e2 = INFINITY;
    int   i0 = 0x7fffffff, i1 = 0x7fffffff, i2 = 0x7fffffff;
    const int mk[TOPM] = { m0, m1, m2, m3, m4 };
    #pragma unroll
    for (int q = 0; q < TOPM; ++q) {
      const int j = mk[q] & 0xFFF;
      const float lx = cand[j];
      const float ly = cand[NL + j];
      const float lz = cand[2 * NL + j];
      const float ll = cand[3 * NL + j];   // exact np-rounded |l|^2 from prep
      const float dot = __fmaf_rn(h2, lz, __fmaf_rn(h1, ly, __fmul_rn(h0, lx)));
      const float d2  = __fadd_rn(__fsub_rn(hh, __fmul_rn(2.0f, dot)), ll);
      lexins3(d2, j, e0, e1, e2, i0, i1, i2);
    }

    // weights: exact diff-form recompute per reference
    const int fm = blockIdx.x * FPB + tid;
    const float H0 = pos_h[fm * 3 + 0];
    const float H1 = pos_h[fm * 3 + 1];
    const float H2 = pos_h[fm * 3 + 2];
    float wk[3];
    int   jk[3] = { i0, i1, i2 };
    #pragma unroll
    for (int k = 0; k < 3; ++k) {
      const int j = jk[k];
      const float dx = __fsub_rn(H0, pos_l[j * 3 + 0]);
      const float dy = __fsub_rn(H1, pos_l[j * 3 + 1]);
      const float dz = __fsub_rn(H2, pos_l[j * 3 + 2]);
      float d2 = __fadd_rn(__fadd_rn(__fmul_rn(dx, dx), __fmul_rn(dy, dy)),
                           __fmul_rn(dz, dz));
      d2 = fmaxf(d2, 1e-16f);
      wk[k] = __frcp_rn(d2);
    }
    const float W  = __fadd_rn(__fadd_rn(wk[0], wk[1]), wk[2]);
    const float rW = __frcp_rn(W);
    #pragma unroll
    for (int k = 0; k < 3; ++k) {
      wn[tid * 3 + k] = wk[k] * rW;
      sj[tid * 3 + k] = jk[k];
    }
  }
  __syncthreads();

  // interpolation: 64 fine x 64 float4 = 4096 tasks, 4 per thread
  const float4* __restrict__ x4   = (const float4*)x;
  float4* __restrict__       out4 = (float4*)out;
  #pragma unroll
  for (int i = 0; i < (FPB * NF4) / BLK; ++i) {
    const int task = tid + i * BLK;
    const int f    = task >> 6;
    const int cc   = task & 63;
    const int j0 = sj[f * 3 + 0], j1 = sj[f * 3 + 1], j2 = sj[f * 3 + 2];
    const float w0 = wn[f * 3 + 0], w1 = wn[f * 3 + 1], w2 = wn[f * 3 + 2];
    const float4 xa = x4[j0 * NF4 + cc];
    const float4 xb = x4[j1 * NF4 + cc];
    const float4 xc = x4[j2 * NF4 + cc];
    float4 r;
    r.x = xa.x * w0 + xb.x * w1 + xc.x * w2;
    r.y = xa.y * w0 + xb.y * w1 + xc.y * w2;
    r.z = xa.z * w0 + xb.z * w1 + xc.z * w2;
    r.w = xa.w * w0 + xb.w * w1 + xc.w * w2;
    out4[(blockIdx.x * FPB + f) * NF4 + cc] = r;
  }
}

extern "C" void kernel_launch(void* const* d_in, const int* in_sizes, int n_in,
                              void* d_out, int out_size, void* d_ws, size_t ws_size,
                              hipStream_t stream)
{
  const float* x     = (const float*)d_in[0];   // [4096, 256]
  const float* pos_l = (const float*)d_in[1];   // [4096, 3]
  const float* pos_h = (const float*)d_in[2];   // [16384, 3]
  float* out  = (float*)d_out;                  // [16384, 256]
  float* cand = (float*)d_ws;                   // SoA x|y|z|ll, 64 KB

  hipLaunchKernelGGL(prep_soa_kernel, dim3(NL / 256), dim3(256), 0, stream,
                     pos_l, cand);
  hipLaunchKernelGGL(knn_interp_kernel, dim3(NH / FPB), dim3(BLK), 0, stream,
                     x, pos_l, pos_h, cand, out);
}